// Round 10
// baseline (92.651 us; speedup 1.0000x reference)
//
#include <hip/hip_runtime.h>

#define BSZ 256
#define SEQ 2048
#define NT  64
#define KS  5.0f

typedef __fp16 half2_t __attribute__((ext_vector_type(2)));
typedef __fp16 half4_t __attribute__((ext_vector_type(4)));
typedef float  f32x4_t __attribute__((ext_vector_type(4)));
typedef int    int2_t  __attribute__((ext_vector_type(2)));

static __device__ __forceinline__ float wave_red_sum(float x) {
#pragma unroll
    for (int d = 1; d < 64; d <<= 1) x += __shfl_xor(x, d);
    return x;
}

static __device__ __forceinline__ half4_t pack4(float a, float b, float c, float d) {
    half2_t lo = __builtin_amdgcn_cvt_pkrtz(a, b);
    half2_t hi = __builtin_amdgcn_cvt_pkrtz(c, d);
    int2_t t;
    t.x = __builtin_bit_cast(int, lo);
    t.y = __builtin_bit_cast(int, hi);
    return __builtin_bit_cast(half4_t, t);
}

// ---------------------------------------------------------------------------
// Fat kernel. Pass1 blocks: 2 waves, wave 0 = forward, wave 1 = backward.
// Each wave advances TWO chunks (2p, 2p+1) of 16 batches as two independent
// dependence chains interleaved per step (ILP); A-fragments shared.
// fwd: X' = F ∘ (E^T X); bwd: X' = E (F ∘ X). D-frag -> next B-frag needs no
// cross-lane movement (same (lane,reg)->(tag,run) map).
// ---------------------------------------------------------------------------
template<int CL>
__global__ __launch_bounds__(128) void crf_fat_kernel(
    const float* __restrict__ logits,
    const int*   __restrict__ tags,
    const int*   __restrict__ mask,
    const float* __restrict__ trans,
    const float* __restrict__ startT,
    const float* __restrict__ endT,
    float* __restrict__ rbuf,    // [BSZ][NCc][NT]
    float* __restrict__ wbuf,    // [BSZ][NCc][NT] (slot 0 unused)
    float* __restrict__ Cf,      // [BSZ][NCc]
    float* __restrict__ numtrans)
{
    constexpr int NCc   = SEQ / CL;
    constexpr int PAIRS = NCc / 2;
    constexpr int P1B   = (BSZ / 16) * PAIRS;

    if ((int)blockIdx.x >= P1B) {
        // ---------------- numerator branch ----------------
        const int b   = blockIdx.x - P1B;
        const int tid = threadIdx.x;
        __shared__ float redf[128];
        __shared__ int   redi[128];

        const int*   __restrict__ tg = tags + (size_t)b * SEQ;
        const int*   __restrict__ mk = mask + (size_t)b * SEQ;
        const float* __restrict__ Lr = logits + (size_t)b * SEQ * NT;

        float acc = 0.0f;
        int   cnt = 0;
        for (int t = tid; t < SEQ; t += 128) {
            int mt  = mk[t];
            cnt += mt;
            int tgt = tg[t] * mt;
            if (t < SEQ - 1) {
                int m1 = mk[t + 1];
                acc += trans[tgt * NT + tg[t + 1] * m1] * (float)m1;
                acc += Lr[t * NT + tgt] * (float)mt;
            }
        }
        redf[tid] = acc;
        redi[tid] = cnt;
        __syncthreads();
        for (int off = 64; off > 0; off >>= 1) {
            if (tid < off) {
                redf[tid] += redf[tid + off];
                redi[tid] += redi[tid + off];
            }
            __syncthreads();
        }
        if (tid == 0) {
            int   last_idx = redi[0] - 1;
            int   m_last   = mk[SEQ - 1];
            int   tag0     = tg[0] * mk[0];
            int   last_tag = tg[last_idx] * mk[last_idx];
            float r = redf[0] + startT[tag0] + endT[last_tag];
            r += Lr[(size_t)(SEQ - 1) * NT + last_tag] * (float)m_last;
            numtrans[b] = r;
        }
        return;
    }

    // ---------------- pass1 branch ----------------
    const int blk  = blockIdx.x;
    const int pr   = blk % PAIRS;
    const int bg   = blk / PAIRS;
    const int cA   = 2 * pr;
    const int cB   = 2 * pr + 1;
    const bool fwd = (threadIdx.x >> 6) == 0;
    const int lane = threadIdx.x & 63;
    const int rlo  = lane & 15;
    const int h    = lane >> 4;
    const int batch = bg * 16 + rlo;

    // A fragments: fwd A = E^T, bwd A = E. Lane l: A[16q+rlo][16kc+4h+i]
    half4_t A[4][4];
#pragma unroll
    for (int q = 0; q < 4; ++q)
#pragma unroll
        for (int kc = 0; kc < 4; ++kc) {
            float e[4];
#pragma unroll
            for (int i = 0; i < 4; ++i) {
                int m = 16 * q + rlo;
                int k = 16 * kc + 4 * h + i;
                e[i] = __expf(fwd ? trans[k * NT + m] : trans[m * NT + k]);
            }
            A[q][kc] = pack4(e[0], e[1], e[2], e[3]);
        }

    const float* __restrict__ Lb  = logits + (size_t)batch * SEQ * NT + 4 * h;
    const int*   __restrict__ mkb = mask + (size_t)batch * SEQ;

    const int dt = fwd ? 1 : -1;

    f32x4_t VA[4], VB[4];
    float CcA = 0.0f, CcB = 0.0f;
    int t0A, nA, t0B, nB;

#pragma unroll
    for (int q = 0; q < 4; ++q)
#pragma unroll
        for (int i = 0; i < 4; ++i) { VA[q][i] = 1.0f; VB[q][i] = 1.0f; }

    if (fwd) {
        if (cA == 0) {
            float mx = -1e30f;
            f32x4_t al[4];
#pragma unroll
            for (int q = 0; q < 4; ++q) {
                f32x4_t em = *(const f32x4_t*)(Lb + 16 * q);   // t = 0
#pragma unroll
                for (int i = 0; i < 4; ++i) {
                    float a = startT[16 * q + 4 * h + i] + em[i];
                    al[q][i] = a;
                    mx = fmaxf(mx, a);
                }
            }
            mx = fmaxf(mx, __shfl_xor(mx, 16));
            mx = fmaxf(mx, __shfl_xor(mx, 32));
            CcA = mx;
#pragma unroll
            for (int q = 0; q < 4; ++q)
#pragma unroll
                for (int i = 0; i < 4; ++i) VA[q][i] = __expf(al[q][i] - mx);
            t0A = 1; nA = CL - 1;
        } else {
            t0A = cA * CL; nA = CL;
        }
        t0B = cB * CL; nB = CL;
    } else {
        if (cA == 0) { t0A = 0; nA = 0; }
        else         { t0A = cA * CL + CL - 1; nA = CL; }
        t0B = cB * CL + CL - 1; nB = CL;
    }

    auto LOADC = [&](int t, f32x4_t (&eb)[4], int& mt) {
#pragma unroll
        for (int q = 0; q < 4; ++q)
            eb[q] = *(const f32x4_t*)(Lb + (size_t)t * NT + 16 * q);
        mt = mkb[t];
    };

    f32x4_t ebA[4], ebB[4];
    int mA = 0, mB = 0;
    if (nA > 0) LOADC(t0A, ebA, mA);
    LOADC(t0B, ebB, mB);

    auto STEP = [&](f32x4_t (&V)[4], float& C, f32x4_t (&eb)[4], int& mref,
                    int t0c, int n, int s) {
        f32x4_t ecur[4];
        int mt = mref;
#pragma unroll
        for (int q = 0; q < 4; ++q) ecur[q] = eb[q];
        int sn = (s + 1 < n) ? s + 1 : n - 1;    // clamped prefetch
        LOADC(t0c + sn * dt, eb, mref);

        half4_t Xh[4];
        if (fwd) {
#pragma unroll
            for (int kc = 0; kc < 4; ++kc)
                Xh[kc] = pack4(V[kc][0], V[kc][1], V[kc][2], V[kc][3]);
        } else {
#pragma unroll
            for (int kc = 0; kc < 4; ++kc) {
                float g0 = __expf(ecur[kc][0] - KS) * V[kc][0];
                float g1 = __expf(ecur[kc][1] - KS) * V[kc][1];
                float g2 = __expf(ecur[kc][2] - KS) * V[kc][2];
                float g3 = __expf(ecur[kc][3] - KS) * V[kc][3];
                Xh[kc] = pack4(g0, g1, g2, g3);
            }
        }

        f32x4_t Y[4];
#pragma unroll
        for (int q = 0; q < 4; ++q) {
            f32x4_t acc = {0.0f, 0.0f, 0.0f, 0.0f};
#pragma unroll
            for (int kc = 0; kc < 4; ++kc)
                acc = __builtin_amdgcn_mfma_f32_16x16x16f16(A[q][kc], Xh[kc], acc, 0, 0, 0);
            Y[q] = acc;
        }

        if (fwd) {
#pragma unroll
            for (int q = 0; q < 4; ++q)
#pragma unroll
                for (int i = 0; i < 4; ++i) {
                    float w = Y[q][i] * __expf(ecur[q][i] - KS);
                    V[q][i] = mt ? w : V[q][i];
                }
            C += mt ? KS : 0.0f;
        } else {
#pragma unroll
            for (int q = 0; q < 4; ++q)
#pragma unroll
                for (int i = 0; i < 4; ++i)
                    V[q][i] = mt ? Y[q][i] : V[q][i];
        }
    };

    auto RENORM = [&](f32x4_t (&V)[4], float& C) {
        float mx = V[0][0];
#pragma unroll
        for (int q = 0; q < 4; ++q)
#pragma unroll
            for (int i = 0; i < 4; ++i) mx = fmaxf(mx, V[q][i]);
        mx = fmaxf(mx, __shfl_xor(mx, 16));
        mx = fmaxf(mx, __shfl_xor(mx, 32));
        float inv = 1.0f / mx;
#pragma unroll
        for (int q = 0; q < 4; ++q)
#pragma unroll
            for (int i = 0; i < 4; ++i) V[q][i] *= inv;
        if (fwd) C += __logf(mx);
    };

    // interleaved dual-chain loop
    for (int s = 0; s < CL; ++s) {
        if (s < nA) STEP(VA, CcA, ebA, mA, t0A, nA, s);
        if (s < nB) STEP(VB, CcB, ebB, mB, t0B, nB, s);
        if ((s & 7) == 7) {
            if (s < nA || nA == CL - 1) RENORM(VA, CcA);
            RENORM(VB, CcB);
        }
    }

    float* outp = fwd ? rbuf : wbuf;
    if (nA > 0 || fwd) {
        float* opA = outp + ((size_t)batch * NCc + cA) * NT + 4 * h;
#pragma unroll
        for (int q = 0; q < 4; ++q) *(f32x4_t*)(opA + 16 * q) = VA[q];
    }
    {
        float* opB = outp + ((size_t)batch * NCc + cB) * NT + 4 * h;
#pragma unroll
        for (int q = 0; q < 4; ++q) *(f32x4_t*)(opB + 16 * q) = VB[q];
    }
    if (fwd && h == 0) {
        Cf[batch * NCc + cA] = CcA;
        Cf[batch * NCc + cB] = CcB;
    }
}

// ---------------------------------------------------------------------------
// Glue, parallelized 4x: block (batch, g) handles junctions c with
// (c-1) % 16 == 4g + w (w = wave in block). Partials to den_part[batch][g].
// den = sum Cf + sum_{c>=1}[log(r_{c-1}.w_c) - log(sum w_c)] + log(r_last.f)
// ---------------------------------------------------------------------------
template<int CL>
__global__ __launch_bounds__(256) void crf_glue_kernel(
    const float* __restrict__ rbuf,
    const float* __restrict__ wbuf,
    const float* __restrict__ Cf,
    const float* __restrict__ endT,
    float* __restrict__ den_part)   // [BSZ][4]
{
    constexpr int NCc = SEQ / CL;
    const int batch = blockIdx.x >> 2;
    const int g     = blockIdx.x & 3;
    const int tid   = threadIdx.x;
    const int lane  = tid & 63;
    const int w     = tid >> 6;

    const float* rb = rbuf + (size_t)batch * NCc * NT;
    const float* wb = wbuf + (size_t)batch * NCc * NT;

    float x = 0.0f;
    if (g == 0) {
        for (int c = tid; c < NCc; c += 256) x += Cf[batch * NCc + c];
    }

    float part = 0.0f;
    for (int c = 1 + 4 * g + w; c < NCc; c += 16) {
        float rprev = rb[(c - 1) * NT + lane];
        float wc    = wb[c * NT + lane];
        float dot = wave_red_sum(rprev * wc);
        float rho = wave_red_sum(wc);
        part += __logf(dot) - __logf(rho);
    }
    if (lane == 0) x += part;
    if (g == 0 && w == 0) {
        float fin = wave_red_sum(rb[(NCc - 1) * NT + lane] * __expf(endT[lane]));
        if (lane == 0) x += __logf(fin);
    }

    __shared__ float sred[256];
    sred[tid] = x;
    __syncthreads();
    for (int off = 128; off > 0; off >>= 1) {
        if (tid < off) sred[tid] += sred[tid + off];
        __syncthreads();
    }
    if (tid == 0) den_part[batch * 4 + g] = sred[0];
}

// ---------------------------------------------------------------------------
// Final scalar reduction: out = sum_b (numtrans[b] - sum_g den_part[b][g]).
// ---------------------------------------------------------------------------
__global__ __launch_bounds__(256) void crf_reduce_kernel(
    const float* __restrict__ den_part,
    const float* __restrict__ numtrans,
    float* __restrict__ out)
{
    __shared__ float red[256];
    const int tid = threadIdx.x;
    float d = den_part[4 * tid] + den_part[4 * tid + 1] +
              den_part[4 * tid + 2] + den_part[4 * tid + 3];
    red[tid] = numtrans[tid] - d;
    __syncthreads();
    for (int off = 128; off > 0; off >>= 1) {
        if (tid < off) red[tid] += red[tid + off];
        __syncthreads();
    }
    if (tid == 0) out[0] = red[0];
}

// ---------------------------------------------------------------------------
template<int CL>
static void launch_all(const float* logits, const int* tags, const int* mask,
                       const float* trans, const float* startT, const float* endT,
                       float* out, float* ws, hipStream_t stream)
{
    constexpr int NCc = SEQ / CL;
    float* den_part = ws;                                    // BSZ*4
    float* numtrans = ws + 4 * BSZ;                          // BSZ
    float* Cf       = numtrans + BSZ;                        // BSZ*NCc
    float* rbuf     = Cf + (size_t)BSZ * NCc;                // BSZ*NCc*NT
    float* wbuf     = rbuf + (size_t)BSZ * NCc * NT;         // BSZ*NCc*NT

    crf_fat_kernel<CL><<<(BSZ / 16) * (NCc / 2) + BSZ, 128, 0, stream>>>(
        logits, tags, mask, trans, startT, endT, rbuf, wbuf, Cf, numtrans);
    crf_glue_kernel<CL><<<BSZ * 4, 256, 0, stream>>>(rbuf, wbuf, Cf, endT, den_part);
    crf_reduce_kernel<<<1, 256, 0, stream>>>(den_part, numtrans, out);
}

template<int CL>
static size_t ws_need() {
    constexpr int NCc = SEQ / CL;
    return ((size_t)5 * BSZ + (size_t)BSZ * NCc +
            2 * (size_t)BSZ * NCc * NT) * sizeof(float);
}

extern "C" void kernel_launch(void* const* d_in, const int* in_sizes, int n_in,
                              void* d_out, int out_size, void* d_ws, size_t ws_size,
                              hipStream_t stream)
{
    const float* logits = (const float*)d_in[0];
    const int*   tags   = (const int*)  d_in[1];
    const int*   mask   = (const int*)  d_in[2];
    const float* trans  = (const float*)d_in[3];
    const float* startT = (const float*)d_in[4];
    const float* endT   = (const float*)d_in[5];
    float* out = (float*)d_out;
    float* ws  = (float*)d_ws;

    if (ws_size >= ws_need<8>()) {
        launch_all<8>(logits, tags, mask, trans, startT, endT, out, ws, stream);
    } else if (ws_size >= ws_need<16>()) {
        launch_all<16>(logits, tags, mask, trans, startT, endT, out, ws, stream);
    } else {
        launch_all<32>(logits, tags, mask, trans, startT, endT, out, ws, stream);
    }
}

// Round 11
// 68.989 us; speedup vs baseline: 1.3430x; 1.3430x over previous
//
#include <hip/hip_runtime.h>

#define BSZ 256
#define SEQ 2048
#define NT  64
#define CL  16          // steps per chunk
#define NC  128         // chunks per sequence
#define SC  256         // steps per superchunk (16 chunks)
#define NG  8           // superchunks per sequence
#define KS  5.0f

#define SROW  136       // LDS bytes per (s,k) row: 64 f16 + 8 pad
#define SSLAB 2184      // LDS bytes per s-slab: 16*136 + 8 pad

typedef __fp16 half2_t __attribute__((ext_vector_type(2)));
typedef __fp16 half4_t __attribute__((ext_vector_type(4)));
typedef float  f32x4_t __attribute__((ext_vector_type(4)));
typedef int    int2_t  __attribute__((ext_vector_type(2)));

static __device__ __forceinline__ float wave_red_sum(float x) {
#pragma unroll
    for (int d = 1; d < 64; d <<= 1) x += __shfl_xor(x, d);
    return x;
}

static __device__ __forceinline__ half4_t pack4(float a, float b, float c, float d) {
    half2_t lo = __builtin_amdgcn_cvt_pkrtz(a, b);
    half2_t hi = __builtin_amdgcn_cvt_pkrtz(c, d);
    int2_t t;
    t.x = __builtin_bit_cast(int, lo);
    t.y = __builtin_bit_cast(int, hi);
    return __builtin_bit_cast(half4_t, t);
}

// ---------------------------------------------------------------------------
// Fat kernel. Blocks [0,BSZ): numerator gather (dispatched FIRST to overlap).
// Blocks [BSZ, BSZ+BSZ*NG): pass1 for (batch b, superchunk g):
//   stage: all 128 threads read the contiguous 64KB logits window
//          [g*256, (g+1)*256) of batch b (fully coalesced), compute
//          F = exp(em - KS) once, store f16 into padded LDS.
//   chains: wave 0 runs 16 forward sub-chunk runs (the 16 MFMA B-columns),
//           wave 1 runs 16 backward runs, both fed from LDS.
//   fwd: X' = F ∘ (E^T X); bwd: X' = E (F ∘ X); D-frag -> next B-frag with
//   no cross-lane movement. Run = sub-chunk k = lane&15; tags by (q, h, i).
//   Per-run 16-bit maskbits: bit s == mask[t]; g==0 run0 bit0 cleared (init).
// ---------------------------------------------------------------------------
__global__ __launch_bounds__(128) void crf_fat_kernel(
    const float* __restrict__ logits,
    const int*   __restrict__ tags,
    const int*   __restrict__ mask,
    const float* __restrict__ trans,
    const float* __restrict__ startT,
    const float* __restrict__ endT,
    float* __restrict__ rbuf,    // [BSZ][NC][NT]
    float* __restrict__ wbuf,    // [BSZ][NC][NT]
    float* __restrict__ Cf,      // [BSZ][NC]
    float* __restrict__ numtrans)
{
    __shared__ __align__(16) unsigned char Flds[16 * SSLAB];
    __shared__ int lmbits[16];

    if (blockIdx.x < BSZ) {
        // ---------------- numerator branch ----------------
        const int b   = blockIdx.x;
        const int tid = threadIdx.x;
        __shared__ float redf[128];
        __shared__ int   redi[128];

        const int*   __restrict__ tg = tags + (size_t)b * SEQ;
        const int*   __restrict__ mk = mask + (size_t)b * SEQ;
        const float* __restrict__ Lr = logits + (size_t)b * SEQ * NT;

        float acc = 0.0f;
        int   cnt = 0;
        for (int t = tid; t < SEQ; t += 128) {
            int mt  = mk[t];
            cnt += mt;
            int tgt = tg[t] * mt;
            if (t < SEQ - 1) {
                int m1 = mk[t + 1];
                acc += trans[tgt * NT + tg[t + 1] * m1] * (float)m1;
                acc += Lr[t * NT + tgt] * (float)mt;
            }
        }
        redf[tid] = acc;
        redi[tid] = cnt;
        __syncthreads();
        for (int off = 64; off > 0; off >>= 1) {
            if (tid < off) {
                redf[tid] += redf[tid + off];
                redi[tid] += redi[tid + off];
            }
            __syncthreads();
        }
        if (tid == 0) {
            int   last_idx = redi[0] - 1;
            int   m_last   = mk[SEQ - 1];
            int   tag0     = tg[0] * mk[0];
            int   last_tag = tg[last_idx] * mk[last_idx];
            float r = redf[0] + startT[tag0] + endT[last_tag];
            r += Lr[(size_t)(SEQ - 1) * NT + last_tag] * (float)m_last;
            numtrans[b] = r;
        }
        return;
    }

    // ---------------- pass1 branch ----------------
    const int blk  = blockIdx.x - BSZ;
    const int b    = blk >> 3;
    const int g    = blk & (NG - 1);
    const int tid  = threadIdx.x;
    const bool fwd = (tid >> 6) == 0;
    const int lane = tid & 63;
    const int rlo  = lane & 15;     // run (sub-chunk) index
    const int h    = lane >> 4;

    // ---- stage F (f16) into LDS: contiguous 64KB window, coalesced ----
    const float* __restrict__ Lg = logits + ((size_t)b * SEQ + (size_t)g * SC) * NT;
#pragma unroll
    for (int rr = 0; rr < 2; ++rr) {
        int row = tid + rr * 128;             // 0..255 (local step)
        int s   = row & 15;
        int k   = row >> 4;
        const float* src = Lg + (size_t)row * NT;
        unsigned char* dst = Flds + s * SSLAB + k * SROW;
#pragma unroll
        for (int jj = 0; jj < 16; ++jj) {
            f32x4_t x = *(const f32x4_t*)(src + jj * 4);
            half2_t p0 = __builtin_amdgcn_cvt_pkrtz(__expf(x[0] - KS), __expf(x[1] - KS));
            half2_t p1 = __builtin_amdgcn_cvt_pkrtz(__expf(x[2] - KS), __expf(x[3] - KS));
            int2_t w;
            w.x = __builtin_bit_cast(int, p0);
            w.y = __builtin_bit_cast(int, p1);
            *(int2_t*)(dst + jj * 8) = w;
        }
    }
    if (tid < 16) {
        const int* mk = mask + (size_t)b * SEQ + (size_t)g * SC + tid * CL;
        int bits = 0;
#pragma unroll
        for (int s = 0; s < CL; ++s) bits |= (mk[s] ? 1 : 0) << s;
        if (g == 0 && tid == 0) bits &= ~1;   // t=0 is the init, not a D-step
        lmbits[tid] = bits;
    }

    // ---- A fragments: fwd A = E^T, bwd A = E. Lane: A[16q+rlo][16kc+4h+i]
    half4_t A[4][4];
#pragma unroll
    for (int q = 0; q < 4; ++q)
#pragma unroll
        for (int kc = 0; kc < 4; ++kc) {
            float e[4];
#pragma unroll
            for (int i = 0; i < 4; ++i) {
                int m = 16 * q + rlo;
                int k = 16 * kc + 4 * h + i;
                e[i] = __expf(fwd ? trans[k * NT + m] : trans[m * NT + k]);
            }
            A[q][kc] = pack4(e[0], e[1], e[2], e[3]);
        }

    __syncthreads();

    const int mbits = lmbits[rlo];
    f32x4_t V[4];
    float C = 0.0f;
#pragma unroll
    for (int q = 0; q < 4; ++q)
#pragma unroll
        for (int i = 0; i < 4; ++i) V[q][i] = 1.0f;

    if (fwd && g == 0 && rlo == 0) {
        // true init for global chunk 0: alpha0 = start + em(t=0)
        float mx = -1e30f;
        f32x4_t al[4];
#pragma unroll
        for (int q = 0; q < 4; ++q) {
            f32x4_t em = *(const f32x4_t*)(logits + (size_t)b * SEQ * NT + 16 * q + 4 * h);
            f32x4_t st = *(const f32x4_t*)(startT + 16 * q + 4 * h);
#pragma unroll
            for (int i = 0; i < 4; ++i) {
                al[q][i] = st[i] + em[i];
                mx = fmaxf(mx, al[q][i]);
            }
        }
        mx = fmaxf(mx, __shfl_xor(mx, 16));
        mx = fmaxf(mx, __shfl_xor(mx, 32));
        C = mx;
#pragma unroll
        for (int q = 0; q < 4; ++q)
#pragma unroll
            for (int i = 0; i < 4; ++i) V[q][i] = __expf(al[q][i] - mx);
    }

    const unsigned char* Fbase = Flds + rlo * SROW + h * 8;

    auto RENORM = [&](bool track) {
        float mx = V[0][0];
#pragma unroll
        for (int q = 0; q < 4; ++q)
#pragma unroll
            for (int i = 0; i < 4; ++i) mx = fmaxf(mx, V[q][i]);
        mx = fmaxf(mx, __shfl_xor(mx, 16));
        mx = fmaxf(mx, __shfl_xor(mx, 32));
        mx = fmaxf(mx, 1e-30f);
        float inv = 1.0f / mx;
#pragma unroll
        for (int q = 0; q < 4; ++q)
#pragma unroll
            for (int i = 0; i < 4; ++i) V[q][i] *= inv;
        if (track) C += __logf(mx);
    };

    if (fwd) {
#pragma unroll
        for (int s = 0; s < CL; ++s) {
            half4_t Fh[4];
#pragma unroll
            for (int q = 0; q < 4; ++q)
                Fh[q] = *(const half4_t*)(Fbase + s * SSLAB + q * 32);
            half4_t Xh[4];
#pragma unroll
            for (int kc = 0; kc < 4; ++kc)
                Xh[kc] = pack4(V[kc][0], V[kc][1], V[kc][2], V[kc][3]);
            f32x4_t Y[4];
#pragma unroll
            for (int q = 0; q < 4; ++q) {
                f32x4_t acc = {0.0f, 0.0f, 0.0f, 0.0f};
#pragma unroll
                for (int kc = 0; kc < 4; ++kc)
                    acc = __builtin_amdgcn_mfma_f32_16x16x16f16(A[q][kc], Xh[kc], acc, 0, 0, 0);
                Y[q] = acc;
            }
            int mt = (mbits >> s) & 1;
#pragma unroll
            for (int q = 0; q < 4; ++q)
#pragma unroll
                for (int i = 0; i < 4; ++i) {
                    float w = Y[q][i] * (float)Fh[q][i];
                    V[q][i] = mt ? w : V[q][i];
                }
            C += mt ? KS : 0.0f;
            if ((s & 7) == 7) RENORM(true);
        }
        float* op = rbuf + ((size_t)b * NC + g * 16 + rlo) * NT + 4 * h;
#pragma unroll
        for (int q = 0; q < 4; ++q) *(f32x4_t*)(op + 16 * q) = V[q];
        if (h == 0) Cf[b * NC + g * 16 + rlo] = C;
    } else {
#pragma unroll
        for (int s = CL - 1; s >= 0; --s) {
            half4_t Fh[4];
#pragma unroll
            for (int kc = 0; kc < 4; ++kc)
                Fh[kc] = *(const half4_t*)(Fbase + s * SSLAB + kc * 32);
            half4_t Xh[4];
#pragma unroll
            for (int kc = 0; kc < 4; ++kc)
                Xh[kc] = pack4(V[kc][0] * (float)Fh[kc][0],
                               V[kc][1] * (float)Fh[kc][1],
                               V[kc][2] * (float)Fh[kc][2],
                               V[kc][3] * (float)Fh[kc][3]);
            f32x4_t Y[4];
#pragma unroll
            for (int q = 0; q < 4; ++q) {
                f32x4_t acc = {0.0f, 0.0f, 0.0f, 0.0f};
#pragma unroll
                for (int kc = 0; kc < 4; ++kc)
                    acc = __builtin_amdgcn_mfma_f32_16x16x16f16(A[q][kc], Xh[kc], acc, 0, 0, 0);
                Y[q] = acc;
            }
            int mt = (mbits >> s) & 1;
#pragma unroll
            for (int q = 0; q < 4; ++q)
#pragma unroll
                for (int i = 0; i < 4; ++i)
                    V[q][i] = mt ? Y[q][i] : V[q][i];
            if ((s & 7) == 0) RENORM(false);
        }
        float* op = wbuf + ((size_t)b * NC + g * 16 + rlo) * NT + 4 * h;
#pragma unroll
        for (int q = 0; q < 4; ++q) *(f32x4_t*)(op + 16 * q) = V[q];
    }
}

// ---------------------------------------------------------------------------
// Glue, parallelized 4x: block (batch, g) handles junctions c with
// (c-1) % 16 == 4g + w. den = sum Cf + sum_{c>=1}[log(r_{c-1}.w_c)
//  - log(sum w_c)] + log(r_{NC-1}.exp(end))
// ---------------------------------------------------------------------------
__global__ __launch_bounds__(256) void crf_glue_kernel(
    const float* __restrict__ rbuf,
    const float* __restrict__ wbuf,
    const float* __restrict__ Cf,
    const float* __restrict__ endT,
    float* __restrict__ den_part)   // [BSZ][4]
{
    const int batch = blockIdx.x >> 2;
    const int g     = blockIdx.x & 3;
    const int tid   = threadIdx.x;
    const int lane  = tid & 63;
    const int w     = tid >> 6;

    const float* rb = rbuf + (size_t)batch * NC * NT;
    const float* wb = wbuf + (size_t)batch * NC * NT;

    float x = 0.0f;
    if (g == 0) {
        for (int c = tid; c < NC; c += 256) x += Cf[batch * NC + c];
    }

    float part = 0.0f;
    for (int c = 1 + 4 * g + w; c < NC; c += 16) {
        float rprev = rb[(c - 1) * NT + lane];
        float wc    = wb[c * NT + lane];
        float dot = wave_red_sum(rprev * wc);
        float rho = wave_red_sum(wc);
        part += __logf(dot) - __logf(rho);
    }
    if (lane == 0) x += part;
    if (g == 0 && w == 0) {
        float fin = wave_red_sum(rb[(NC - 1) * NT + lane] * __expf(endT[lane]));
        if (lane == 0) x += __logf(fin);
    }

    __shared__ float sred[256];
    sred[tid] = x;
    __syncthreads();
    for (int off = 128; off > 0; off >>= 1) {
        if (tid < off) sred[tid] += sred[tid + off];
        __syncthreads();
    }
    if (tid == 0) den_part[batch * 4 + g] = sred[0];
}

// ---------------------------------------------------------------------------
// Final scalar reduction: out = sum_b (numtrans[b] - sum_g den_part[b][g]).
// ---------------------------------------------------------------------------
__global__ __launch_bounds__(256) void crf_reduce_kernel(
    const float* __restrict__ den_part,
    const float* __restrict__ numtrans,
    float* __restrict__ out)
{
    __shared__ float red[256];
    const int tid = threadIdx.x;
    float d = den_part[4 * tid] + den_part[4 * tid + 1] +
              den_part[4 * tid + 2] + den_part[4 * tid + 3];
    red[tid] = numtrans[tid] - d;
    __syncthreads();
    for (int off = 128; off > 0; off >>= 1) {
        if (tid < off) red[tid] += red[tid + off];
        __syncthreads();
    }
    if (tid == 0) out[0] = red[0];
}

// ---------------------------------------------------------------------------
extern "C" void kernel_launch(void* const* d_in, const int* in_sizes, int n_in,
                              void* d_out, int out_size, void* d_ws, size_t ws_size,
                              hipStream_t stream)
{
    const float* logits = (const float*)d_in[0];
    const int*   tags   = (const int*)  d_in[1];
    const int*   mask   = (const int*)  d_in[2];
    const float* trans  = (const float*)d_in[3];
    const float* startT = (const float*)d_in[4];
    const float* endT   = (const float*)d_in[5];
    float* out = (float*)d_out;
    float* ws  = (float*)d_ws;

    float* den_part = ws;                                    // BSZ*4
    float* numtrans = ws + 4 * BSZ;                          // BSZ
    float* Cf       = numtrans + BSZ;                        // BSZ*NC
    float* rbuf     = Cf + (size_t)BSZ * NC;                 // BSZ*NC*NT
    float* wbuf     = rbuf + (size_t)BSZ * NC * NT;          // BSZ*NC*NT

    crf_fat_kernel<<<BSZ + BSZ * NG, 128, 0, stream>>>(
        logits, tags, mask, trans, startT, endT, rbuf, wbuf, Cf, numtrans);
    crf_glue_kernel<<<BSZ * 4, 256, 0, stream>>>(rbuf, wbuf, Cf, endT, den_part);
    crf_reduce_kernel<<<1, 256, 0, stream>>>(den_part, numtrans, out);
}